// Round 2
// baseline (292.857 us; speedup 1.0000x reference)
//
#include <hip/hip_runtime.h>

#define N_NODES 50000
#define N_EDGES 800000
#define D_INF 64
#define D_HIDF 128

// ---------------------------------------------------------------------------
// CSR build: zero -> histogram -> scan -> fill
// ---------------------------------------------------------------------------

__global__ void zero_kernel(int* __restrict__ p, int n) {
    int i = blockIdx.x * blockDim.x + threadIdx.x;
    if (i < n) p[i] = 0;
}

__global__ void hist_kernel(const int* __restrict__ dst, int* __restrict__ cnt) {
    int e = blockIdx.x * blockDim.x + threadIdx.x;
    if (e < N_EDGES) atomicAdd(&cnt[dst[e]], 1);
}

// Single-block (1024-thread, 16-wave) chunked inclusive scan -> rowptr[1..N]
__global__ void __launch_bounds__(1024) scan_kernel(const int* __restrict__ cnt,
                                                    int* __restrict__ rowptr) {
    __shared__ int wsum[16];
    __shared__ int s_carry;
    int tid = threadIdx.x;
    int lane = tid & 63;
    int wv = tid >> 6;
    if (tid == 0) { s_carry = 0; rowptr[0] = 0; }
    __syncthreads();
    for (int base = 0; base < N_NODES; base += 1024) {
        int idx = base + tid;
        int v = (idx < N_NODES) ? cnt[idx] : 0;
        // inclusive scan within wave
#pragma unroll
        for (int off = 1; off < 64; off <<= 1) {
            int t = __shfl_up(v, off);
            if (lane >= off) v += t;
        }
        if (lane == 63) wsum[wv] = v;
        __syncthreads();
        if (wv == 0) {
            int t = (lane < 16) ? wsum[lane] : 0;
#pragma unroll
            for (int off = 1; off < 16; off <<= 1) {
                int u = __shfl_up(t, off);
                if (lane >= off) t += u;
            }
            if (lane < 16) wsum[lane] = t;
        }
        __syncthreads();
        int woff = (wv > 0) ? wsum[wv - 1] : 0;
        int total = wsum[15];
        if (idx < N_NODES) rowptr[idx + 1] = s_carry + woff + v;
        __syncthreads();
        if (tid == 0) s_carry += total;
        __syncthreads();
    }
}

__global__ void fill_kernel(const int* __restrict__ src, const int* __restrict__ dst,
                            const int* __restrict__ rowptr, int* __restrict__ cursor,
                            int* __restrict__ elist) {
    int e = blockIdx.x * blockDim.x + threadIdx.x;
    if (e < N_EDGES) {
        int t = dst[e];
        int pos = rowptr[t] + atomicAdd(&cursor[t], 1);
        elist[pos] = src[e];
    }
}

// One wave per node: lane d accumulates feature d over the node's edge list.
// agg = x + sum_{neighbors} x[src]   (EPS = 0 folded)
__global__ void __launch_bounds__(256) gather_kernel(const float* __restrict__ x,
                                                     const int* __restrict__ rowptr,
                                                     const int* __restrict__ elist,
                                                     float* __restrict__ agg) {
    int wid = (blockIdx.x * blockDim.x + threadIdx.x) >> 6;
    int lane = threadIdx.x & 63;
    if (wid >= N_NODES) return;
    int beg = rowptr[wid];
    int end = rowptr[wid + 1];
    float s = x[(size_t)wid * D_INF + lane];
    int e = beg;
    for (; e + 3 < end; e += 4) {
        int s0 = elist[e + 0];
        int s1 = elist[e + 1];
        int s2 = elist[e + 2];
        int s3 = elist[e + 3];
        float v0 = x[(size_t)s0 * D_INF + lane];
        float v1 = x[(size_t)s1 * D_INF + lane];
        float v2 = x[(size_t)s2 * D_INF + lane];
        float v3 = x[(size_t)s3 * D_INF + lane];
        s += (v0 + v1) + (v2 + v3);
    }
    for (; e < end; e++) {
        s += x[(size_t)elist[e] * D_INF + lane];
    }
    agg[(size_t)wid * D_INF + lane] = s;
}

// ---------------------------------------------------------------------------
// MLP
// ---------------------------------------------------------------------------

__global__ void transpose_w1_kernel(const float* __restrict__ W1, float* __restrict__ W1T) {
    int i = blockIdx.x * blockDim.x + threadIdx.x;
    if (i < D_INF * D_HIDF) {
        int l = i / D_HIDF;
        int j = i % D_HIDF;
        W1T[j * D_INF + l] = W1[i];
    }
}

__global__ void __launch_bounds__(256) mlp_kernel(const float* __restrict__ agg,
                                                  const float* __restrict__ W1T,
                                                  const float* __restrict__ b1,
                                                  const float* __restrict__ W2,
                                                  const float* __restrict__ b2,
                                                  float* __restrict__ out) {
    int n = blockIdx.x * blockDim.x + threadIdx.x;
    if (n >= N_NODES) return;

    float h[D_INF];
    const float4* aggv = reinterpret_cast<const float4*>(agg + (size_t)n * D_INF);
#pragma unroll
    for (int i = 0; i < D_INF / 4; i++) {
        float4 v = aggv[i];
        h[4 * i + 0] = v.x;
        h[4 * i + 1] = v.y;
        h[4 * i + 2] = v.z;
        h[4 * i + 3] = v.w;
    }

    float acc[D_INF];
#pragma unroll
    for (int d = 0; d < D_INF; d++) acc[d] = b2[d];

#pragma unroll 4
    for (int j = 0; j < D_HIDF; j++) {
        const float* w = W1T + j * D_INF;
        float s0 = 0.f, s1 = 0.f, s2 = 0.f, s3 = 0.f;
#pragma unroll
        for (int l = 0; l < D_INF; l += 4) {
            s0 += h[l + 0] * w[l + 0];
            s1 += h[l + 1] * w[l + 1];
            s2 += h[l + 2] * w[l + 2];
            s3 += h[l + 3] * w[l + 3];
        }
        float s = b1[j] + ((s0 + s1) + (s2 + s3));
        s = fmaxf(s, 0.0f);
        const float* w2 = W2 + j * D_INF;
#pragma unroll
        for (int d = 0; d < D_INF; d++) {
            acc[d] += s * w2[d];
        }
    }

    float4* outv = reinterpret_cast<float4*>(out + (size_t)n * D_INF);
#pragma unroll
    for (int i = 0; i < D_INF / 4; i++) {
        outv[i] = make_float4(acc[4 * i + 0], acc[4 * i + 1], acc[4 * i + 2], acc[4 * i + 3]);
    }
}

// ---------------------------------------------------------------------------
// Fallback (round-1 atomic scatter) — used only if ws_size is too small
// ---------------------------------------------------------------------------

__global__ void init_agg_kernel(const float* __restrict__ x, float* __restrict__ agg) {
    int i = blockIdx.x * blockDim.x + threadIdx.x;
    int n4 = N_NODES * D_INF / 4;
    if (i < n4) {
        reinterpret_cast<float4*>(agg)[i] = reinterpret_cast<const float4*>(x)[i];
    }
}

__global__ void scatter_kernel(const float* __restrict__ x,
                               const int* __restrict__ src,
                               const int* __restrict__ dst,
                               float* __restrict__ agg) {
    int tid = blockIdx.x * blockDim.x + threadIdx.x;
    int e = tid >> 6;
    int d = tid & 63;
    if (e < N_EDGES) {
        atomicAdd(&agg[(size_t)dst[e] * D_INF + d], x[(size_t)src[e] * D_INF + d]);
    }
}

// ---------------------------------------------------------------------------

extern "C" void kernel_launch(void* const* d_in, const int* in_sizes, int n_in,
                              void* d_out, int out_size, void* d_ws, size_t ws_size,
                              hipStream_t stream) {
    const float* x   = (const float*)d_in[0];
    const int* edge  = (const int*)d_in[1];   // [2, E]: src = edge, dst = edge + E
    const float* W1  = (const float*)d_in[2];
    const float* b1  = (const float*)d_in[3];
    const float* W2  = (const float*)d_in[4];
    const float* b2  = (const float*)d_in[5];
    float* out       = (float*)d_out;

    const int* src = edge;
    const int* dst = edge + N_EDGES;

    // Workspace layout (floats first, 16B-aligned base assumed):
    //   agg  : N*64 floats        (12.8 MB)
    //   W1T  : 128*64 floats      (32 KB)
    //   cnt  : N ints
    //   cursor: N ints
    //   rowptr: N+1 ints
    //   elist : E ints            (3.2 MB)
    float* agg = (float*)d_ws;
    float* W1T = agg + (size_t)N_NODES * D_INF;
    int* cnt    = (int*)(W1T + D_INF * D_HIDF);
    int* cursor = cnt + N_NODES;
    int* rowptr = cursor + N_NODES;
    int* elist  = rowptr + N_NODES + 1;

    size_t needed = ((size_t)N_NODES * D_INF + D_INF * D_HIDF) * 4
                  + ((size_t)3 * N_NODES + 1 + N_EDGES) * 4;

    // W1 transpose (needed by both paths)
    {
        int n = D_INF * D_HIDF;
        transpose_w1_kernel<<<(n + 255) / 256, 256, 0, stream>>>(W1, W1T);
    }

    if (ws_size >= needed) {
        // CSR build
        zero_kernel<<<(2 * N_NODES + 255) / 256, 256, 0, stream>>>(cnt, 2 * N_NODES);
        hist_kernel<<<(N_EDGES + 255) / 256, 256, 0, stream>>>(dst, cnt);
        scan_kernel<<<1, 1024, 0, stream>>>(cnt, rowptr);
        fill_kernel<<<(N_EDGES + 255) / 256, 256, 0, stream>>>(src, dst, rowptr, cursor, elist);
        // Gather (agg = x + neighbor sum)
        {
            int threads = N_NODES * 64;
            gather_kernel<<<(threads + 255) / 256, 256, 0, stream>>>(x, rowptr, elist, agg);
        }
    } else {
        // Fallback: atomic scatter
        int n4 = N_NODES * D_INF / 4;
        init_agg_kernel<<<(n4 + 255) / 256, 256, 0, stream>>>(x, agg);
        int work = N_EDGES * D_INF;
        scatter_kernel<<<(work + 255) / 256, 256, 0, stream>>>(x, src, dst, agg);
    }

    // Fused MLP
    mlp_kernel<<<(N_NODES + 255) / 256, 256, 0, stream>>>(agg, W1T, b1, W2, b2, out);
}

// Round 3
// 291.877 us; speedup vs baseline: 1.0034x; 1.0034x over previous
//
#include <hip/hip_runtime.h>

#define N_NODES 50000
#define N_EDGES 800000
#define D_INF 64
#define D_HIDF 128

// ---------------------------------------------------------------------------
// CSR build: zero -> histogram -> scan -> fill
// ---------------------------------------------------------------------------

__global__ void zero_kernel(int* __restrict__ p, int n) {
    int i = blockIdx.x * blockDim.x + threadIdx.x;
    if (i < n) p[i] = 0;
}

__global__ void hist_kernel(const int* __restrict__ dst, int* __restrict__ cnt) {
    int e = blockIdx.x * blockDim.x + threadIdx.x;
    if (e < N_EDGES) atomicAdd(&cnt[dst[e]], 1);
}

// Single-block (1024-thread, 16-wave) chunked inclusive scan -> rowptr[1..N]
__global__ void __launch_bounds__(1024) scan_kernel(const int* __restrict__ cnt,
                                                    int* __restrict__ rowptr) {
    __shared__ int wsum[16];
    __shared__ int s_carry;
    int tid = threadIdx.x;
    int lane = tid & 63;
    int wv = tid >> 6;
    if (tid == 0) { s_carry = 0; rowptr[0] = 0; }
    __syncthreads();
    for (int base = 0; base < N_NODES; base += 1024) {
        int idx = base + tid;
        int v = (idx < N_NODES) ? cnt[idx] : 0;
        // inclusive scan within wave
#pragma unroll
        for (int off = 1; off < 64; off <<= 1) {
            int t = __shfl_up(v, off);
            if (lane >= off) v += t;
        }
        if (lane == 63) wsum[wv] = v;
        __syncthreads();
        if (wv == 0) {
            int t = (lane < 16) ? wsum[lane] : 0;
#pragma unroll
            for (int off = 1; off < 16; off <<= 1) {
                int u = __shfl_up(t, off);
                if (lane >= off) t += u;
            }
            if (lane < 16) wsum[lane] = t;
        }
        __syncthreads();
        int woff = (wv > 0) ? wsum[wv - 1] : 0;
        int total = wsum[15];
        if (idx < N_NODES) rowptr[idx + 1] = s_carry + woff + v;
        __syncthreads();
        if (tid == 0) s_carry += total;
        __syncthreads();
    }
}

__global__ void fill_kernel(const int* __restrict__ src, const int* __restrict__ dst,
                            const int* __restrict__ rowptr, int* __restrict__ cursor,
                            int* __restrict__ elist) {
    int e = blockIdx.x * blockDim.x + threadIdx.x;
    if (e < N_EDGES) {
        int t = dst[e];
        int pos = rowptr[t] + atomicAdd(&cursor[t], 1);
        elist[pos] = src[e];
    }
}

// One wave per node: lane d accumulates feature d over the node's edge list.
// agg = x + sum_{neighbors} x[src]   (EPS = 0 folded)
__global__ void __launch_bounds__(256) gather_kernel(const float* __restrict__ x,
                                                     const int* __restrict__ rowptr,
                                                     const int* __restrict__ elist,
                                                     float* __restrict__ agg) {
    int wid = (blockIdx.x * blockDim.x + threadIdx.x) >> 6;
    int lane = threadIdx.x & 63;
    if (wid >= N_NODES) return;
    int beg = rowptr[wid];
    int end = rowptr[wid + 1];
    float s = x[(size_t)wid * D_INF + lane];
    int e = beg;
    for (; e + 3 < end; e += 4) {
        int s0 = elist[e + 0];
        int s1 = elist[e + 1];
        int s2 = elist[e + 2];
        int s3 = elist[e + 3];
        float v0 = x[(size_t)s0 * D_INF + lane];
        float v1 = x[(size_t)s1 * D_INF + lane];
        float v2 = x[(size_t)s2 * D_INF + lane];
        float v3 = x[(size_t)s3 * D_INF + lane];
        s += (v0 + v1) + (v2 + v3);
    }
    for (; e < end; e++) {
        s += x[(size_t)elist[e] * D_INF + lane];
    }
    agg[(size_t)wid * D_INF + lane] = s;
}

// ---------------------------------------------------------------------------
// MLP
// ---------------------------------------------------------------------------

__global__ void transpose_w1_kernel(const float* __restrict__ W1, float* __restrict__ W1T) {
    int i = blockIdx.x * blockDim.x + threadIdx.x;
    if (i < D_INF * D_HIDF) {
        int l = i / D_HIDF;
        int j = i % D_HIDF;
        W1T[j * D_INF + l] = W1[i];
    }
}

__global__ void __launch_bounds__(256) mlp_kernel(const float* __restrict__ agg,
                                                  const float* __restrict__ W1T,
                                                  const float* __restrict__ b1,
                                                  const float* __restrict__ W2,
                                                  const float* __restrict__ b2,
                                                  float* __restrict__ out) {
    int n = blockIdx.x * blockDim.x + threadIdx.x;
    if (n >= N_NODES) return;

    float h[D_INF];
    const float4* aggv = reinterpret_cast<const float4*>(agg + (size_t)n * D_INF);
#pragma unroll
    for (int i = 0; i < D_INF / 4; i++) {
        float4 v = aggv[i];
        h[4 * i + 0] = v.x;
        h[4 * i + 1] = v.y;
        h[4 * i + 2] = v.z;
        h[4 * i + 3] = v.w;
    }

    float acc[D_INF];
#pragma unroll
    for (int d = 0; d < D_INF; d++) acc[d] = b2[d];

#pragma unroll 4
    for (int j = 0; j < D_HIDF; j++) {
        const float* w = W1T + j * D_INF;
        float s0 = 0.f, s1 = 0.f, s2 = 0.f, s3 = 0.f;
#pragma unroll
        for (int l = 0; l < D_INF; l += 4) {
            s0 += h[l + 0] * w[l + 0];
            s1 += h[l + 1] * w[l + 1];
            s2 += h[l + 2] * w[l + 2];
            s3 += h[l + 3] * w[l + 3];
        }
        float s = b1[j] + ((s0 + s1) + (s2 + s3));
        s = fmaxf(s, 0.0f);
        const float* w2 = W2 + j * D_INF;
#pragma unroll
        for (int d = 0; d < D_INF; d++) {
            acc[d] += s * w2[d];
        }
    }

    float4* outv = reinterpret_cast<float4*>(out + (size_t)n * D_INF);
#pragma unroll
    for (int i = 0; i < D_INF / 4; i++) {
        outv[i] = make_float4(acc[4 * i + 0], acc[4 * i + 1], acc[4 * i + 2], acc[4 * i + 3]);
    }
}

// ---------------------------------------------------------------------------
// Fallback (round-1 atomic scatter) — used only if ws_size is too small
// ---------------------------------------------------------------------------

__global__ void init_agg_kernel(const float* __restrict__ x, float* __restrict__ agg) {
    int i = blockIdx.x * blockDim.x + threadIdx.x;
    int n4 = N_NODES * D_INF / 4;
    if (i < n4) {
        reinterpret_cast<float4*>(agg)[i] = reinterpret_cast<const float4*>(x)[i];
    }
}

__global__ void scatter_kernel(const float* __restrict__ x,
                               const int* __restrict__ src,
                               const int* __restrict__ dst,
                               float* __restrict__ agg) {
    int tid = blockIdx.x * blockDim.x + threadIdx.x;
    int e = tid >> 6;
    int d = tid & 63;
    if (e < N_EDGES) {
        atomicAdd(&agg[(size_t)dst[e] * D_INF + d], x[(size_t)src[e] * D_INF + d]);
    }
}

// ---------------------------------------------------------------------------

extern "C" void kernel_launch(void* const* d_in, const int* in_sizes, int n_in,
                              void* d_out, int out_size, void* d_ws, size_t ws_size,
                              hipStream_t stream) {
    const float* x   = (const float*)d_in[0];
    const int* edge  = (const int*)d_in[1];   // [2, E]: src = edge, dst = edge + E
    const float* W1  = (const float*)d_in[2];
    const float* b1  = (const float*)d_in[3];
    const float* W2  = (const float*)d_in[4];
    const float* b2  = (const float*)d_in[5];
    float* out       = (float*)d_out;

    const int* src = edge;
    const int* dst = edge + N_EDGES;

    // Workspace layout (floats first, 16B-aligned base assumed):
    //   agg  : N*64 floats        (12.8 MB)
    //   W1T  : 128*64 floats      (32 KB)
    //   cnt  : N ints
    //   cursor: N ints
    //   rowptr: N+1 ints
    //   elist : E ints            (3.2 MB)
    float* agg = (float*)d_ws;
    float* W1T = agg + (size_t)N_NODES * D_INF;
    int* cnt    = (int*)(W1T + D_INF * D_HIDF);
    int* cursor = cnt + N_NODES;
    int* rowptr = cursor + N_NODES;
    int* elist  = rowptr + N_NODES + 1;

    size_t needed = ((size_t)N_NODES * D_INF + D_INF * D_HIDF) * 4
                  + ((size_t)3 * N_NODES + 1 + N_EDGES) * 4;

    // W1 transpose (needed by both paths)
    {
        int n = D_INF * D_HIDF;
        transpose_w1_kernel<<<(n + 255) / 256, 256, 0, stream>>>(W1, W1T);
    }

    if (ws_size >= needed) {
        // CSR build
        zero_kernel<<<(2 * N_NODES + 255) / 256, 256, 0, stream>>>(cnt, 2 * N_NODES);
        hist_kernel<<<(N_EDGES + 255) / 256, 256, 0, stream>>>(dst, cnt);
        scan_kernel<<<1, 1024, 0, stream>>>(cnt, rowptr);
        fill_kernel<<<(N_EDGES + 255) / 256, 256, 0, stream>>>(src, dst, rowptr, cursor, elist);
        // Gather (agg = x + neighbor sum)
        {
            int threads = N_NODES * 64;
            gather_kernel<<<(threads + 255) / 256, 256, 0, stream>>>(x, rowptr, elist, agg);
        }
    } else {
        // Fallback: atomic scatter
        int n4 = N_NODES * D_INF / 4;
        init_agg_kernel<<<(n4 + 255) / 256, 256, 0, stream>>>(x, agg);
        int work = N_EDGES * D_INF;
        scatter_kernel<<<(work + 255) / 256, 256, 0, stream>>>(x, src, dst, agg);
    }

    // Fused MLP
    mlp_kernel<<<(N_NODES + 255) / 256, 256, 0, stream>>>(agg, W1T, b1, W2, b2, out);
}

// Round 4
// 225.408 us; speedup vs baseline: 1.2992x; 1.2949x over previous
//
#include <hip/hip_runtime.h>

#define N_NODES 50000
#define N_EDGES 800000
#define D_INF 64
#define D_HIDF 128

#define SCAN_CHUNK 1024
#define SCAN_NBLK ((N_NODES + SCAN_CHUNK - 1) / SCAN_CHUNK)  // 49

// ---------------------------------------------------------------------------
// CSR build: zero -> histogram -> 3-pass scan -> fill
// ---------------------------------------------------------------------------

__global__ void zero_kernel(int* __restrict__ p, int n) {
    int i = blockIdx.x * blockDim.x + threadIdx.x;
    if (i < n) p[i] = 0;
}

__global__ void hist_kernel(const int* __restrict__ dst, int* __restrict__ cnt) {
    int e = blockIdx.x * blockDim.x + threadIdx.x;
    if (e < N_EDGES) atomicAdd(&cnt[dst[e]], 1);
}

// Pass 1: per-block (1024-element chunk) scan; rowptr[i+1] = local inclusive,
// block total -> bsum[b].
__global__ void __launch_bounds__(256) scan1_kernel(const int* __restrict__ cnt,
                                                    int* __restrict__ rowptr,
                                                    int* __restrict__ bsum) {
    __shared__ int wsum[4];
    int tid = threadIdx.x;
    int lane = tid & 63;
    int wv = tid >> 6;
    int base = blockIdx.x * SCAN_CHUNK + tid * 4;

    int v0 = 0, v1 = 0, v2 = 0, v3 = 0;
    if (base + 3 < N_NODES) {
        int4 q = *reinterpret_cast<const int4*>(cnt + base);
        v0 = q.x; v1 = q.y; v2 = q.z; v3 = q.w;
    } else {
        if (base + 0 < N_NODES) v0 = cnt[base + 0];
        if (base + 1 < N_NODES) v1 = cnt[base + 1];
        if (base + 2 < N_NODES) v2 = cnt[base + 2];
        if (base + 3 < N_NODES) v3 = cnt[base + 3];
    }
    int s = v0 + v1 + v2 + v3;
    int incl = s;
#pragma unroll
    for (int off = 1; off < 64; off <<= 1) {
        int t = __shfl_up(incl, off);
        if (lane >= off) incl += t;
    }
    if (lane == 63) wsum[wv] = incl;
    __syncthreads();
    if (tid == 0) {
        wsum[1] += wsum[0];
        wsum[2] += wsum[1];
        wsum[3] += wsum[2];
    }
    __syncthreads();
    int off0 = ((wv > 0) ? wsum[wv - 1] : 0) + (incl - s);
    int p0 = off0 + v0, p1 = p0 + v1, p2 = p1 + v2, p3 = p2 + v3;
    if (base + 0 < N_NODES) rowptr[base + 1] = p0;
    if (base + 1 < N_NODES) rowptr[base + 2] = p1;
    if (base + 2 < N_NODES) rowptr[base + 3] = p2;
    if (base + 3 < N_NODES) rowptr[base + 4] = p3;
    if (tid == 0) {
        bsum[blockIdx.x] = wsum[3];
        if (blockIdx.x == 0) rowptr[0] = 0;
    }
}

// Pass 2: one wave scans the 49 block sums -> exclusive offsets in place.
__global__ void scan2_kernel(int* __restrict__ bsum) {
    int lane = threadIdx.x;  // blockDim = 64
    int v = (lane < SCAN_NBLK) ? bsum[lane] : 0;
    int incl = v;
#pragma unroll
    for (int off = 1; off < 64; off <<= 1) {
        int t = __shfl_up(incl, off);
        if (lane >= off) incl += t;
    }
    if (lane < SCAN_NBLK) bsum[lane] = incl - v;
}

// Pass 3: add block offsets.
__global__ void scan3_kernel(int* __restrict__ rowptr, const int* __restrict__ bsum) {
    int add = bsum[blockIdx.x];
    if (add == 0) return;  // uniform per block (block 0)
    int base = blockIdx.x * SCAN_CHUNK + threadIdx.x * 4;
#pragma unroll
    for (int i = 0; i < 4; i++) {
        if (base + i < N_NODES) rowptr[base + i + 1] += add;
    }
}

__global__ void fill_kernel(const int* __restrict__ src, const int* __restrict__ dst,
                            const int* __restrict__ rowptr, int* __restrict__ cursor,
                            int* __restrict__ elist) {
    int e = blockIdx.x * blockDim.x + threadIdx.x;
    if (e < N_EDGES) {
        int t = dst[e];
        int pos = rowptr[t] + atomicAdd(&cursor[t], 1);
        elist[pos] = src[e];
    }
}

// One wave per node: lane d accumulates feature d over the node's edge list.
// agg = x + sum_{neighbors} x[src]   (EPS = 0 folded)
__global__ void __launch_bounds__(256) gather_kernel(const float* __restrict__ x,
                                                     const int* __restrict__ rowptr,
                                                     const int* __restrict__ elist,
                                                     float* __restrict__ agg) {
    int wid = (blockIdx.x * blockDim.x + threadIdx.x) >> 6;
    int lane = threadIdx.x & 63;
    if (wid >= N_NODES) return;
    int beg = rowptr[wid];
    int end = rowptr[wid + 1];
    float s = x[(size_t)wid * D_INF + lane];
    int e = beg;
    for (; e + 3 < end; e += 4) {
        int s0 = elist[e + 0];
        int s1 = elist[e + 1];
        int s2 = elist[e + 2];
        int s3 = elist[e + 3];
        float v0 = x[(size_t)s0 * D_INF + lane];
        float v1 = x[(size_t)s1 * D_INF + lane];
        float v2 = x[(size_t)s2 * D_INF + lane];
        float v3 = x[(size_t)s3 * D_INF + lane];
        s += (v0 + v1) + (v2 + v3);
    }
    for (; e < end; e++) {
        s += x[(size_t)elist[e] * D_INF + lane];
    }
    agg[(size_t)wid * D_INF + lane] = s;
}

// ---------------------------------------------------------------------------
// MLP v2: 16 nodes/block, 256 threads, LDS-tiled, weights via L1.
// ---------------------------------------------------------------------------

#define MLP_NB 16
#define AGG_LD 68    // padded row stride (floats): 68 % 32 = 4 -> conflict-free
#define H_LD 132     // 132 % 32 = 4

__global__ void __launch_bounds__(256) mlp_kernel(const float* __restrict__ agg,
                                                  const float* __restrict__ W1,
                                                  const float* __restrict__ b1,
                                                  const float* __restrict__ W2,
                                                  const float* __restrict__ b2,
                                                  float* __restrict__ out) {
    __shared__ float aggs[MLP_NB * AGG_LD];
    __shared__ float hs[MLP_NB * H_LD];
    int tid = threadIdx.x;
    int nb = blockIdx.x * MLP_NB;  // base node of this block
    int n = tid >> 4;              // 0..15 local node
    int sub = tid & 15;            // 0..15

    // stage agg tile: thread t loads 16B, block covers 16 nodes x 64 floats
    {
        float4 v = *reinterpret_cast<const float4*>(agg + (size_t)nb * D_INF + tid * 4);
        *reinterpret_cast<float4*>(&aggs[n * AGG_LD + sub * 4]) = v;
    }
    __syncthreads();

    // phase 1: h[n][j] for j = sub*8 .. sub*8+7
    {
        float h[8];
        float4 bb0 = *reinterpret_cast<const float4*>(b1 + sub * 8);
        float4 bb1 = *reinterpret_cast<const float4*>(b1 + sub * 8 + 4);
        h[0] = bb0.x; h[1] = bb0.y; h[2] = bb0.z; h[3] = bb0.w;
        h[4] = bb1.x; h[5] = bb1.y; h[6] = bb1.z; h[7] = bb1.w;
#pragma unroll 4
        for (int l4 = 0; l4 < 16; l4++) {
            float4 a = *reinterpret_cast<const float4*>(&aggs[n * AGG_LD + l4 * 4]);
            float av[4] = {a.x, a.y, a.z, a.w};
#pragma unroll
            for (int i = 0; i < 4; i++) {
                const float* w = W1 + (l4 * 4 + i) * D_HIDF + sub * 8;
                float4 w0 = *reinterpret_cast<const float4*>(w);
                float4 w1 = *reinterpret_cast<const float4*>(w + 4);
                h[0] += av[i] * w0.x;
                h[1] += av[i] * w0.y;
                h[2] += av[i] * w0.z;
                h[3] += av[i] * w0.w;
                h[4] += av[i] * w1.x;
                h[5] += av[i] * w1.y;
                h[6] += av[i] * w1.z;
                h[7] += av[i] * w1.w;
            }
        }
#pragma unroll
        for (int k = 0; k < 8; k++) h[k] = fmaxf(h[k], 0.0f);
        *reinterpret_cast<float4*>(&hs[n * H_LD + sub * 8]) =
            make_float4(h[0], h[1], h[2], h[3]);
        *reinterpret_cast<float4*>(&hs[n * H_LD + sub * 8 + 4]) =
            make_float4(h[4], h[5], h[6], h[7]);
    }
    __syncthreads();

    // phase 2: out[n][d] for d = sub*4 .. sub*4+3
    {
        float4 bb = *reinterpret_cast<const float4*>(b2 + sub * 4);
        float a0 = bb.x, a1 = bb.y, a2 = bb.z, a3 = bb.w;
#pragma unroll 8
        for (int j4 = 0; j4 < 32; j4++) {
            float4 hv = *reinterpret_cast<const float4*>(&hs[n * H_LD + j4 * 4]);
            float hvv[4] = {hv.x, hv.y, hv.z, hv.w};
#pragma unroll
            for (int i = 0; i < 4; i++) {
                float4 w = *reinterpret_cast<const float4*>(W2 + (j4 * 4 + i) * D_INF + sub * 4);
                a0 += hvv[i] * w.x;
                a1 += hvv[i] * w.y;
                a2 += hvv[i] * w.z;
                a3 += hvv[i] * w.w;
            }
        }
        *reinterpret_cast<float4*>(out + (size_t)(nb + n) * D_INF + sub * 4) =
            make_float4(a0, a1, a2, a3);
    }
}

// ---------------------------------------------------------------------------
// Fallback (atomic scatter) — used only if ws_size is too small
// ---------------------------------------------------------------------------

__global__ void init_agg_kernel(const float* __restrict__ x, float* __restrict__ agg) {
    int i = blockIdx.x * blockDim.x + threadIdx.x;
    int n4 = N_NODES * D_INF / 4;
    if (i < n4) {
        reinterpret_cast<float4*>(agg)[i] = reinterpret_cast<const float4*>(x)[i];
    }
}

__global__ void scatter_kernel(const float* __restrict__ x,
                               const int* __restrict__ src,
                               const int* __restrict__ dst,
                               float* __restrict__ agg) {
    int tid = blockIdx.x * blockDim.x + threadIdx.x;
    int e = tid >> 6;
    int d = tid & 63;
    if (e < N_EDGES) {
        atomicAdd(&agg[(size_t)dst[e] * D_INF + d], x[(size_t)src[e] * D_INF + d]);
    }
}

// ---------------------------------------------------------------------------

extern "C" void kernel_launch(void* const* d_in, const int* in_sizes, int n_in,
                              void* d_out, int out_size, void* d_ws, size_t ws_size,
                              hipStream_t stream) {
    const float* x   = (const float*)d_in[0];
    const int* edge  = (const int*)d_in[1];   // [2, E]: src = edge, dst = edge + E
    const float* W1  = (const float*)d_in[2];
    const float* b1  = (const float*)d_in[3];
    const float* W2  = (const float*)d_in[4];
    const float* b2  = (const float*)d_in[5];
    float* out       = (float*)d_out;

    const int* src = edge;
    const int* dst = edge + N_EDGES;

    // Workspace layout:
    //   agg   : N*64 floats (12.8 MB)
    //   cnt   : N ints
    //   cursor: N ints
    //   rowptr: N+1 ints
    //   bsum  : 64 ints
    //   elist : E ints (3.2 MB)
    float* agg  = (float*)d_ws;
    int* cnt    = (int*)(agg + (size_t)N_NODES * D_INF);
    int* cursor = cnt + N_NODES;
    int* rowptr = cursor + N_NODES;
    int* bsum   = rowptr + N_NODES + 1;
    int* elist  = bsum + 64;

    size_t needed = ((size_t)N_NODES * D_INF) * 4
                  + ((size_t)3 * N_NODES + 1 + 64 + N_EDGES) * 4;

    if (ws_size >= needed) {
        zero_kernel<<<(2 * N_NODES + 255) / 256, 256, 0, stream>>>(cnt, 2 * N_NODES);
        hist_kernel<<<(N_EDGES + 255) / 256, 256, 0, stream>>>(dst, cnt);
        scan1_kernel<<<SCAN_NBLK, 256, 0, stream>>>(cnt, rowptr, bsum);
        scan2_kernel<<<1, 64, 0, stream>>>(bsum);
        scan3_kernel<<<SCAN_NBLK, 256, 0, stream>>>(rowptr, bsum);
        fill_kernel<<<(N_EDGES + 255) / 256, 256, 0, stream>>>(src, dst, rowptr, cursor, elist);
        int threads = N_NODES * 64;
        gather_kernel<<<(threads + 255) / 256, 256, 0, stream>>>(x, rowptr, elist, agg);
    } else {
        int n4 = N_NODES * D_INF / 4;
        init_agg_kernel<<<(n4 + 255) / 256, 256, 0, stream>>>(x, agg);
        int work = N_EDGES * D_INF;
        scatter_kernel<<<(work + 255) / 256, 256, 0, stream>>>(x, src, dst, agg);
    }

    // MLP: 16 nodes per block
    mlp_kernel<<<N_NODES / MLP_NB, 256, 0, stream>>>(agg, W1, b1, W2, b2, out);
}

// Round 5
// 187.918 us; speedup vs baseline: 1.5584x; 1.1995x over previous
//
#include <hip/hip_runtime.h>

#define N_NODES 50000
#define N_EDGES 800000
#define D_INF 64
#define D_HIDF 128

#define SCAN_CHUNK 1024
#define SCAN_NBLK ((N_NODES + SCAN_CHUNK - 1) / SCAN_CHUNK)  // 49

// ---------------------------------------------------------------------------
// CSR build: zero -> histogram -> 3-pass scan -> fill
// ---------------------------------------------------------------------------

__global__ void zero_kernel(int* __restrict__ p, int n) {
    int i = blockIdx.x * blockDim.x + threadIdx.x;
    if (i < n) p[i] = 0;
}

__global__ void hist_kernel(const int* __restrict__ dst, int* __restrict__ cnt) {
    int e = blockIdx.x * blockDim.x + threadIdx.x;
    if (e < N_EDGES) atomicAdd(&cnt[dst[e]], 1);
}

__global__ void __launch_bounds__(256) scan1_kernel(const int* __restrict__ cnt,
                                                    int* __restrict__ rowptr,
                                                    int* __restrict__ bsum) {
    __shared__ int wsum[4];
    int tid = threadIdx.x;
    int lane = tid & 63;
    int wv = tid >> 6;
    int base = blockIdx.x * SCAN_CHUNK + tid * 4;

    int v0 = 0, v1 = 0, v2 = 0, v3 = 0;
    if (base + 3 < N_NODES) {
        int4 q = *reinterpret_cast<const int4*>(cnt + base);
        v0 = q.x; v1 = q.y; v2 = q.z; v3 = q.w;
    } else {
        if (base + 0 < N_NODES) v0 = cnt[base + 0];
        if (base + 1 < N_NODES) v1 = cnt[base + 1];
        if (base + 2 < N_NODES) v2 = cnt[base + 2];
        if (base + 3 < N_NODES) v3 = cnt[base + 3];
    }
    int s = v0 + v1 + v2 + v3;
    int incl = s;
#pragma unroll
    for (int off = 1; off < 64; off <<= 1) {
        int t = __shfl_up(incl, off);
        if (lane >= off) incl += t;
    }
    if (lane == 63) wsum[wv] = incl;
    __syncthreads();
    if (tid == 0) {
        wsum[1] += wsum[0];
        wsum[2] += wsum[1];
        wsum[3] += wsum[2];
    }
    __syncthreads();
    int off0 = ((wv > 0) ? wsum[wv - 1] : 0) + (incl - s);
    int p0 = off0 + v0, p1 = p0 + v1, p2 = p1 + v2, p3 = p2 + v3;
    if (base + 0 < N_NODES) rowptr[base + 1] = p0;
    if (base + 1 < N_NODES) rowptr[base + 2] = p1;
    if (base + 2 < N_NODES) rowptr[base + 3] = p2;
    if (base + 3 < N_NODES) rowptr[base + 4] = p3;
    if (tid == 0) {
        bsum[blockIdx.x] = wsum[3];
        if (blockIdx.x == 0) rowptr[0] = 0;
    }
}

__global__ void scan2_kernel(int* __restrict__ bsum) {
    int lane = threadIdx.x;  // blockDim = 64
    int v = (lane < SCAN_NBLK) ? bsum[lane] : 0;
    int incl = v;
#pragma unroll
    for (int off = 1; off < 64; off <<= 1) {
        int t = __shfl_up(incl, off);
        if (lane >= off) incl += t;
    }
    if (lane < SCAN_NBLK) bsum[lane] = incl - v;
}

__global__ void scan3_kernel(int* __restrict__ rowptr, const int* __restrict__ bsum) {
    int add = bsum[blockIdx.x];
    if (add == 0) return;
    int base = blockIdx.x * SCAN_CHUNK + threadIdx.x * 4;
#pragma unroll
    for (int i = 0; i < 4; i++) {
        if (base + i < N_NODES) rowptr[base + i + 1] += add;
    }
}

__global__ void fill_kernel(const int* __restrict__ src, const int* __restrict__ dst,
                            const int* __restrict__ rowptr, int* __restrict__ cursor,
                            int* __restrict__ elist) {
    int e = blockIdx.x * blockDim.x + threadIdx.x;
    if (e < N_EDGES) {
        int t = dst[e];
        int pos = rowptr[t] + atomicAdd(&cursor[t], 1);
        elist[pos] = src[e];
    }
}

// One wave per node: lane d accumulates feature d over the node's edge list.
// agg = x + sum_{neighbors} x[src]   (EPS = 0 folded)
__global__ void __launch_bounds__(256) gather_kernel(const float* __restrict__ x,
                                                     const int* __restrict__ rowptr,
                                                     const int* __restrict__ elist,
                                                     float* __restrict__ agg) {
    int wid = (blockIdx.x * blockDim.x + threadIdx.x) >> 6;
    int lane = threadIdx.x & 63;
    if (wid >= N_NODES) return;
    int beg = rowptr[wid];
    int end = rowptr[wid + 1];
    float s = x[(size_t)wid * D_INF + lane];
    float s2 = 0.f;
    int e = beg;
    for (; e + 7 < end; e += 8) {
        int i0 = elist[e + 0];
        int i1 = elist[e + 1];
        int i2 = elist[e + 2];
        int i3 = elist[e + 3];
        int i4 = elist[e + 4];
        int i5 = elist[e + 5];
        int i6 = elist[e + 6];
        int i7 = elist[e + 7];
        float v0 = x[(size_t)i0 * D_INF + lane];
        float v1 = x[(size_t)i1 * D_INF + lane];
        float v2 = x[(size_t)i2 * D_INF + lane];
        float v3 = x[(size_t)i3 * D_INF + lane];
        float v4 = x[(size_t)i4 * D_INF + lane];
        float v5 = x[(size_t)i5 * D_INF + lane];
        float v6 = x[(size_t)i6 * D_INF + lane];
        float v7 = x[(size_t)i7 * D_INF + lane];
        s += (v0 + v1) + (v2 + v3);
        s2 += (v4 + v5) + (v6 + v7);
    }
    for (; e < end; e++) {
        s += x[(size_t)elist[e] * D_INF + lane];
    }
    agg[(size_t)wid * D_INF + lane] = s + s2;
}

// ---------------------------------------------------------------------------
// MLP v3: 16 nodes/block, 256 threads, W1+W2 staged in LDS (loaded once per
// block), agg/h tiles in LDS. FMA-bound by construction.
// ---------------------------------------------------------------------------

#define MLP_NB 16
#define AGG_LD 68    // 68 % 32 = 4 -> conflict-free row stride
#define H_LD 132     // 132 % 32 = 4

__global__ void __launch_bounds__(256) mlp_kernel(const float* __restrict__ agg,
                                                  const float* __restrict__ W1,
                                                  const float* __restrict__ b1,
                                                  const float* __restrict__ W2,
                                                  const float* __restrict__ b2,
                                                  float* __restrict__ out) {
    __shared__ float w1s[D_INF * D_HIDF];   // 32 KB
    __shared__ float w2s[D_HIDF * D_INF];   // 32 KB
    __shared__ float aggs[MLP_NB * AGG_LD]; // 4.3 KB
    __shared__ float hs[MLP_NB * H_LD];     // 8.4 KB
    int tid = threadIdx.x;
    int nb = blockIdx.x * MLP_NB;
    int n = tid >> 4;    // 0..15 local node
    int sub = tid & 15;  // 0..15

    // stage weights: 8192 floats each = 8 float4 per thread per matrix
#pragma unroll
    for (int i = 0; i < 8; i++) {
        int o = (i * 256 + tid) * 4;
        *reinterpret_cast<float4*>(&w1s[o]) = *reinterpret_cast<const float4*>(W1 + o);
        *reinterpret_cast<float4*>(&w2s[o]) = *reinterpret_cast<const float4*>(W2 + o);
    }
    // stage agg tile
    {
        float4 v = *reinterpret_cast<const float4*>(agg + (size_t)nb * D_INF + tid * 4);
        *reinterpret_cast<float4*>(&aggs[n * AGG_LD + sub * 4]) = v;
    }
    __syncthreads();

    // phase 1: h[n][j] for j = sub*8 .. sub*8+7
    {
        float h[8];
        float4 bb0 = *reinterpret_cast<const float4*>(b1 + sub * 8);
        float4 bb1 = *reinterpret_cast<const float4*>(b1 + sub * 8 + 4);
        h[0] = bb0.x; h[1] = bb0.y; h[2] = bb0.z; h[3] = bb0.w;
        h[4] = bb1.x; h[5] = bb1.y; h[6] = bb1.z; h[7] = bb1.w;
#pragma unroll 4
        for (int l4 = 0; l4 < 16; l4++) {
            float4 a = *reinterpret_cast<const float4*>(&aggs[n * AGG_LD + l4 * 4]);
            float av[4] = {a.x, a.y, a.z, a.w};
#pragma unroll
            for (int i = 0; i < 4; i++) {
                const float* w = &w1s[(l4 * 4 + i) * D_HIDF + sub * 8];
                float4 w0 = *reinterpret_cast<const float4*>(w);
                float4 w1 = *reinterpret_cast<const float4*>(w + 4);
                h[0] += av[i] * w0.x;
                h[1] += av[i] * w0.y;
                h[2] += av[i] * w0.z;
                h[3] += av[i] * w0.w;
                h[4] += av[i] * w1.x;
                h[5] += av[i] * w1.y;
                h[6] += av[i] * w1.z;
                h[7] += av[i] * w1.w;
            }
        }
#pragma unroll
        for (int k = 0; k < 8; k++) h[k] = fmaxf(h[k], 0.0f);
        *reinterpret_cast<float4*>(&hs[n * H_LD + sub * 8]) =
            make_float4(h[0], h[1], h[2], h[3]);
        *reinterpret_cast<float4*>(&hs[n * H_LD + sub * 8 + 4]) =
            make_float4(h[4], h[5], h[6], h[7]);
    }
    __syncthreads();

    // phase 2: out[n][d] for d = sub*4 .. sub*4+3
    {
        float4 bb = *reinterpret_cast<const float4*>(b2 + sub * 4);
        float a0 = bb.x, a1 = bb.y, a2 = bb.z, a3 = bb.w;
#pragma unroll 8
        for (int j4 = 0; j4 < 32; j4++) {
            float4 hv = *reinterpret_cast<const float4*>(&hs[n * H_LD + j4 * 4]);
            float hvv[4] = {hv.x, hv.y, hv.z, hv.w};
#pragma unroll
            for (int i = 0; i < 4; i++) {
                float4 w = *reinterpret_cast<const float4*>(&w2s[(j4 * 4 + i) * D_INF + sub * 4]);
                a0 += hvv[i] * w.x;
                a1 += hvv[i] * w.y;
                a2 += hvv[i] * w.z;
                a3 += hvv[i] * w.w;
            }
        }
        *reinterpret_cast<float4*>(out + (size_t)(nb + n) * D_INF + sub * 4) =
            make_float4(a0, a1, a2, a3);
    }
}

// ---------------------------------------------------------------------------
// Fallback (atomic scatter) — used only if ws_size is too small
// ---------------------------------------------------------------------------

__global__ void init_agg_kernel(const float* __restrict__ x, float* __restrict__ agg) {
    int i = blockIdx.x * blockDim.x + threadIdx.x;
    int n4 = N_NODES * D_INF / 4;
    if (i < n4) {
        reinterpret_cast<float4*>(agg)[i] = reinterpret_cast<const float4*>(x)[i];
    }
}

__global__ void scatter_kernel(const float* __restrict__ x,
                               const int* __restrict__ src,
                               const int* __restrict__ dst,
                               float* __restrict__ agg) {
    int tid = blockIdx.x * blockDim.x + threadIdx.x;
    int e = tid >> 6;
    int d = tid & 63;
    if (e < N_EDGES) {
        atomicAdd(&agg[(size_t)dst[e] * D_INF + d], x[(size_t)src[e] * D_INF + d]);
    }
}

// ---------------------------------------------------------------------------

extern "C" void kernel_launch(void* const* d_in, const int* in_sizes, int n_in,
                              void* d_out, int out_size, void* d_ws, size_t ws_size,
                              hipStream_t stream) {
    const float* x   = (const float*)d_in[0];
    const int* edge  = (const int*)d_in[1];   // [2, E]: src = edge, dst = edge + E
    const float* W1  = (const float*)d_in[2];
    const float* b1  = (const float*)d_in[3];
    const float* W2  = (const float*)d_in[4];
    const float* b2  = (const float*)d_in[5];
    float* out       = (float*)d_out;

    const int* src = edge;
    const int* dst = edge + N_EDGES;

    float* agg  = (float*)d_ws;
    int* cnt    = (int*)(agg + (size_t)N_NODES * D_INF);
    int* cursor = cnt + N_NODES;
    int* rowptr = cursor + N_NODES;
    int* bsum   = rowptr + N_NODES + 1;
    int* elist  = bsum + 64;

    size_t needed = ((size_t)N_NODES * D_INF) * 4
                  + ((size_t)3 * N_NODES + 1 + 64 + N_EDGES) * 4;

    if (ws_size >= needed) {
        zero_kernel<<<(2 * N_NODES + 255) / 256, 256, 0, stream>>>(cnt, 2 * N_NODES);
        hist_kernel<<<(N_EDGES + 255) / 256, 256, 0, stream>>>(dst, cnt);
        scan1_kernel<<<SCAN_NBLK, 256, 0, stream>>>(cnt, rowptr, bsum);
        scan2_kernel<<<1, 64, 0, stream>>>(bsum);
        scan3_kernel<<<SCAN_NBLK, 256, 0, stream>>>(rowptr, bsum);
        fill_kernel<<<(N_EDGES + 255) / 256, 256, 0, stream>>>(src, dst, rowptr, cursor, elist);
        int threads = N_NODES * 64;
        gather_kernel<<<(threads + 255) / 256, 256, 0, stream>>>(x, rowptr, elist, agg);
    } else {
        int n4 = N_NODES * D_INF / 4;
        init_agg_kernel<<<(n4 + 255) / 256, 256, 0, stream>>>(x, agg);
        int work = N_EDGES * D_INF;
        scatter_kernel<<<(work + 255) / 256, 256, 0, stream>>>(x, src, dst, agg);
    }

    // MLP: 16 nodes per block, weights LDS-resident
    mlp_kernel<<<N_NODES / MLP_NB, 256, 0, stream>>>(agg, W1, b1, W2, b2, out);
}